// Round 6
// baseline (285.344 us; speedup 1.0000x reference)
//
#include <hip/hip_runtime.h>
#include <hip/hip_cooperative_groups.h>

namespace cg = cooperative_groups;

// SGC: out = A^K (x w) + b, A = D^-1/2 (Adj+I) D^-1/2, K=2, on per-node scalars y = x.w.
// History: device-scope atomics ~16.7 G/s (48us/pass) -> binned LDS accumulation (63us).
// R5 lesson: k_bin write pattern irrelevant -> suspect per-dispatch overhead (~4-5us x 9).
// R6: ONE cooperative kernel, 3 grid.sync()s, zero device atomics, per-chunk owner blocks
// with LDS-persistent dis + dense compacted edge lists.

#define TB        256
#define RECS      7
#define TILE      (RECS*TB)      // 1792
#define CHUNK_LG  10
#define CHUNK     1024
#define NCH       64             // max chunks
#define CAPB      224            // record capacity per (tile,chunk): mean 36.6, sd 6 -> 31 sigma
#define MAXTILES  512

__global__ __launch_bounds__(TB, 2)
void k_fused(const float* __restrict__ x, const int* __restrict__ src,
             const int* __restrict__ dst, const float* __restrict__ W,
             const float* __restrict__ bias,
             int n, int E, int C, int ntiles, int dcap, int G,
             unsigned* __restrict__ binned, int* __restrict__ bcnt,
             unsigned* __restrict__ dense,
             float* __restrict__ y, float* __restrict__ u,
             float* __restrict__ u2, float* __restrict__ out)
{
    cg::grid_group grid = cg::this_grid();
    __shared__ int      hist[NCH], base_[NCH], cur[NCH];
    __shared__ unsigned recs[TILE];         // 7 KB   (bin phase)
    __shared__ float    accf[CHUNK];        // 4 KB   (hop accumulator)
    __shared__ float    disL[CHUNK];        // 4 KB   (persists P2->P4)
    __shared__ int      scanb[MAXTILES];    // 2 KB   (persists P2->P4)
    __shared__ int      s_dtot;

    const int t   = threadIdx.x;
    const int bid = blockIdx.x;

    // ---------- P1a: bin edges into (tile,chunk) runs; rec = (dst_local<<16)|src ----------
    for (int b = bid; b < ntiles; b += G) {
        if (t < NCH) hist[t] = 0;
        __syncthreads();
        int e0 = b * TILE;
        int nrec = E - e0; if (nrec > TILE) nrec = TILE;
        unsigned rec[RECS]; int ch[RECS];
        #pragma unroll
        for (int k = 0; k < RECS; k++) {
            int e = e0 + k * TB + t;
            if (e < E) {
                int s = src[e], d = dst[e];
                ch[k]  = d >> CHUNK_LG;
                rec[k] = ((unsigned)ch[k] << 26) | ((unsigned)(d & (CHUNK - 1)) << 16) | (unsigned)s;
                atomicAdd(&hist[ch[k]], 1);
            } else ch[k] = -1;
        }
        __syncthreads();
        if (t < NCH) {   // wave 0: 64-lane inclusive scan
            int h = hist[t], v = h;
            #pragma unroll
            for (int off = 1; off < 64; off <<= 1) {
                int w = __shfl_up(v, off);
                if (t >= off) v += w;
            }
            base_[t] = v - h; cur[t] = v - h;
            bcnt[b * NCH + t] = (h > CAPB) ? CAPB : h;
        }
        __syncthreads();
        #pragma unroll
        for (int k = 0; k < RECS; k++)
            if (ch[k] >= 0) recs[atomicAdd(&cur[ch[k]], 1)] = rec[k];
        __syncthreads();
        for (int j = t; j < nrec; j += TB) {        // coalesced run writes
            unsigned r = recs[j];
            int c2 = r >> 26, off = j - base_[c2];
            if (off < CAPB)
                binned[((size_t)b * NCH + c2) * CAPB + off] = r & 0x03FFFFFFu;
        }
        __syncthreads();
    }

    // ---------- P1b: y = x . w  (one wave per node) ----------
    {
        const float2 wv = ((const float2*)W)[t & 63];
        int lane = t & 63;
        int gw   = (bid * TB + t) >> 6;
        int nw   = (G * TB) >> 6;
        for (int i = gw; i < n; i += nw) {
            float2 xv = ((const float2*)(x + (size_t)i * 128))[lane];
            float v = xv.x * wv.x + xv.y * wv.y;
            #pragma unroll
            for (int off = 32; off; off >>= 1) v += __shfl_xor(v, off);
            if (lane == 0) y[i] = v;
        }
    }
    grid.sync();

    const int c = bid;
    // ---------- P2: compact chunk records to dense + degree + epi0 ----------
    if (c < C) {
        for (int j = t; j < MAXTILES; j += TB) scanb[j] = (j < ntiles) ? bcnt[j * NCH + c] : 0;
        __syncthreads();
        #pragma unroll
        for (int off = 1; off < MAXTILES; off <<= 1) {   // Hillis-Steele, 2 elems/thread
            int i1 = t, i2 = t + TB;
            int a1 = (i1 >= off) ? scanb[i1 - off] : 0;
            int a2 = (i2 >= off) ? scanb[i2 - off] : 0;
            __syncthreads();
            scanb[i1] += a1; scanb[i2] += a2;
            __syncthreads();
        }
        if (t == 0) s_dtot = scanb[ntiles - 1];
        for (int l = t; l < CHUNK; l += TB) accf[l] = 0.f;
        __syncthreads();
        int grp = t >> 6, ln = t & 63;
        unsigned* dn = dense + (size_t)c * dcap;
        for (int b = grp; b < ntiles; b += 4) {          // 4 wave-groups over tiles
            int o0 = b ? scanb[b - 1] : 0;
            int nc = scanb[b] - o0;
            const unsigned* run = binned + ((size_t)b * NCH + c) * CAPB;
            for (int j = ln; j < nc; j += 64) {
                unsigned r = run[j];
                if (o0 + j < dcap) dn[o0 + j] = r;
                atomicAdd(&accf[r >> 16], 1.0f);         // degree
            }
        }
        __syncthreads();
        for (int l = t; l < CHUNK; l += TB) {
            int i = (c << CHUNK_LG) + l;
            if (i < n) {
                float d = rsqrtf(accf[l] + 1.0f);        // +1 self-loop
                disL[l] = d;
                u[i] = d * y[i];
            }
        }
    }
    grid.sync();

    // ---------- P3: hop1 + epi1 ----------
    if (c < C) {
        for (int l = t; l < CHUNK; l += TB) accf[l] = 0.f;
        __syncthreads();
        const unsigned* dn = dense + (size_t)c * dcap;
        int tot = s_dtot; if (tot > dcap) tot = dcap;
        for (int j = t; j < tot; j += TB) {
            unsigned r = dn[j];
            atomicAdd(&accf[r >> 16], u[r & 0xFFFFu]);
        }
        __syncthreads();
        for (int l = t; l < CHUNK; l += TB) {
            int i = (c << CHUNK_LG) + l;
            if (i < n) {
                float d = disL[l];
                u2[i] = d * d * (accf[l] + u[i]);
            }
        }
    }
    grid.sync();

    // ---------- P4: hop2 + epi2 -> out ----------
    if (c < C) {
        for (int l = t; l < CHUNK; l += TB) accf[l] = 0.f;
        __syncthreads();
        const unsigned* dn = dense + (size_t)c * dcap;
        int tot = s_dtot; if (tot > dcap) tot = dcap;
        for (int j = t; j < tot; j += TB) {
            unsigned r = dn[j];
            atomicAdd(&accf[r >> 16], u2[r & 0xFFFFu]);
        }
        __syncthreads();
        float bb = bias[0];
        for (int l = t; l < CHUNK; l += TB) {
            int i = (c << CHUNK_LG) + l;
            if (i < n) out[i] = disL[l] * (accf[l] + u2[i]) + bb;
        }
    }
}

// ---------------- fallback multi-kernel path (proven, ~63 us) ----------------
#define NSLAB 16
#define MAXC  64

__global__ void k_zero(int* __restrict__ cnt) { cnt[threadIdx.x] = 0; }

__global__ void k_bin(const int* __restrict__ src, const int* __restrict__ dst,
                      int E, int nchunks, int cap,
                      int* __restrict__ cnt, unsigned int* __restrict__ binned) {
    __shared__ int hist[MAXC], base[MAXC], cur[MAXC];
    int t = threadIdx.x;
    if (t < MAXC) { hist[t] = 0; cur[t] = 0; }
    __syncthreads();
    int e0 = blockIdx.x * (RECS * 256);
    unsigned int rec[RECS]; int ch[RECS];
    #pragma unroll
    for (int k = 0; k < RECS; k++) {
        int e = e0 + k * 256 + t;
        if (e < E) {
            int s = src[e], d = dst[e];
            ch[k]  = d >> CHUNK_LG;
            rec[k] = ((unsigned)(d & (CHUNK - 1)) << 16) | (unsigned)s;
            atomicAdd(&hist[ch[k]], 1);
        } else ch[k] = -1;
    }
    __syncthreads();
    if (t < nchunks) base[t] = atomicAdd(&cnt[t], hist[t]);
    __syncthreads();
    #pragma unroll
    for (int k = 0; k < RECS; k++) {
        if (ch[k] >= 0) {
            int slot = base[ch[k]] + atomicAdd(&cur[ch[k]], 1);
            if (slot < cap) binned[(size_t)ch[k] * cap + slot] = rec[k];
        }
    }
}

template <int MODE>
__global__ void k_hop(const unsigned int* __restrict__ binned, const int* __restrict__ cnt,
                      int cap, const float* __restrict__ val, float* __restrict__ partial) {
    __shared__ float acc[CHUNK];
    int c = blockIdx.x >> 4;
    int m = blockIdx.x & (NSLAB - 1);
    int t = threadIdx.x;
    #pragma unroll
    for (int k = 0; k < CHUNK / 256; k++) acc[t + k * 256] = 0.f;
    __syncthreads();
    int nc = cnt[c]; if (nc > cap) nc = cap;
    const unsigned int* bb = binned + (size_t)c * cap;
    for (int e = m * 256 + t; e < nc; e += NSLAB * 256) {
        unsigned int r = bb[e];
        float v = (MODE == 0) ? 1.0f : val[r & 0xFFFFu];
        atomicAdd(&acc[r >> 16], v);
    }
    __syncthreads();
    float* pp = partial + ((size_t)(c * NSLAB + m) << CHUNK_LG);
    #pragma unroll
    for (int k = 0; k < CHUNK / 256; k++) pp[t + k * 256] = acc[t + k * 256];
}

__global__ void k_dot(const float* __restrict__ x, const float* __restrict__ W,
                      float* __restrict__ y, int n) {
    int wid  = (blockIdx.x * blockDim.x + threadIdx.x) >> 6;
    int lane = threadIdx.x & 63;
    if (wid >= n) return;
    const float2* xr = (const float2*)(x + (size_t)wid * 128);
    float2 xv = xr[lane];
    float2 wv = ((const float2*)W)[lane];
    float v = xv.x * wv.x + xv.y * wv.y;
    #pragma unroll
    for (int off = 32; off; off >>= 1) v += __shfl_xor(v, off);
    if (lane == 0) y[wid] = v;
}

template <int V>
__global__ void k_reduce(const float* __restrict__ partial, int n,
                         const float* __restrict__ y, float* __restrict__ dis,
                         float* __restrict__ u, float* __restrict__ u2,
                         const float* __restrict__ b, float* __restrict__ out) {
    int i = blockIdx.x * blockDim.x + threadIdx.x;
    if (i >= n) return;
    int c = i >> CHUNK_LG, l = i & (CHUNK - 1);
    const float* pp = partial + ((size_t)(c * NSLAB) << CHUNK_LG) + l;
    float s = 0.f;
    #pragma unroll
    for (int m = 0; m < NSLAB; m++) s += pp[m << CHUNK_LG];
    if (V == 0) { float d = rsqrtf(s + 1.0f); dis[i] = d; u[i] = d * y[i]; }
    if (V == 1) { float d = dis[i]; u2[i] = d * d * (s + u[i]); }
    if (V == 2) { out[i] = dis[i] * (s + u2[i]) + b[0]; }
}

extern "C" void kernel_launch(void* const* d_in, const int* in_sizes, int n_in,
                              void* d_out, int out_size, void* d_ws, size_t ws_size,
                              hipStream_t stream) {
    const float* x  = (const float*)d_in[0];
    const int*   ei = (const int*)d_in[1];
    const float* W  = (const float*)d_in[2];
    const float* b  = (const float*)d_in[3];
    float* out = (float*)d_out;

    const int n = out_size;
    const int E = in_sizes[1] / 2;
    const int D = in_sizes[0] / n;
    const int* src = ei;
    const int* dst = ei + E;

    const int C      = (n + CHUNK - 1) >> CHUNK_LG;
    const int ntiles = (E + TILE - 1) / TILE;
    const int dcap   = (E / (C > 0 ? C : 1)) * 5 / 4 + 2048;

    // fused-path ws layout (words): binned | bcnt | dense | y | u | u2
    size_t w_binned = (size_t)ntiles * NCH * CAPB;
    size_t w_bcnt   = (size_t)ntiles * NCH;
    size_t w_dense  = (size_t)C * dcap;
    size_t need     = (w_binned + w_bcnt + w_dense + 3 * (size_t)n) * 4;

    if (D == 128 && n <= 65536 && C <= NCH && ntiles <= MAXTILES && ws_size >= need) {
        unsigned* binned = (unsigned*)d_ws;
        int*      bcnt   = (int*)d_ws + w_binned;
        unsigned* dense  = (unsigned*)d_ws + w_binned + w_bcnt;
        float*    y      = (float*)d_ws + w_binned + w_bcnt + w_dense;
        float*    u      = y + n;
        float*    u2     = u + n;

        int G = 448;
        int occ = 0;
        if (hipOccupancyMaxActiveBlocksPerMultiprocessor(&occ, (const void*)k_fused, TB, 0)
                == hipSuccess && occ >= 1) {
            int cap = occ * 256;                // 256 CUs on MI355X
            if (G > cap) G = cap;
        }
        if (G < C) G = C;

        void* args[] = { (void*)&x, (void*)&src, (void*)&dst, (void*)&W, (void*)&b,
                         (void*)&n, (void*)&E, (void*)&C, (void*)&ntiles, (void*)&dcap, (void*)&G,
                         (void*)&binned, (void*)&bcnt, (void*)&dense,
                         (void*)&y, (void*)&u, (void*)&u2, (void*)&out };
        hipError_t err = hipLaunchCooperativeKernel((void*)k_fused, dim3(G), dim3(TB),
                                                    args, 0, stream);
        if (err == hipSuccess) return;
        (void)hipGetLastError();   // clear; fall through to fallback
    }

    // fallback: proven binned multi-kernel path
    {
        const int TBf = 256;
        const int cap = (int)((long long)E * 5 / (4 * C)) + 512;
        int*          cnt    = (int*)d_ws;
        unsigned int* binned = (unsigned int*)(cnt + 64);
        float*        part   = (float*)(binned + (size_t)C * cap);
        float*        y      = part + (size_t)C * NSLAB * CHUNK;
        float*        dis    = y + n;
        float*        u      = dis + n;
        float*        u2     = u + n;

        const int binBlocks = (E + RECS * 256 - 1) / (RECS * 256);
        const int hopBlocks = C * NSLAB;
        const int nb        = (n + TBf - 1) / TBf;
        const int dotBlocks = ((size_t)n * 64 + TBf - 1) / TBf;

        k_zero<<<1, 64, 0, stream>>>(cnt);
        k_bin<<<binBlocks, TBf, 0, stream>>>(src, dst, E, C, cap, cnt, binned);
        k_dot<<<dotBlocks, TBf, 0, stream>>>(x, W, y, n);
        k_hop<0><<<hopBlocks, TBf, 0, stream>>>(binned, cnt, cap, y, part);
        k_reduce<0><<<nb, TBf, 0, stream>>>(part, n, y, dis, u, u2, b, out);
        k_hop<1><<<hopBlocks, TBf, 0, stream>>>(binned, cnt, cap, u, part);
        k_reduce<1><<<nb, TBf, 0, stream>>>(part, n, y, dis, u, u2, b, out);
        k_hop<1><<<hopBlocks, TBf, 0, stream>>>(binned, cnt, cap, u2, part);
        k_reduce<2><<<nb, TBf, 0, stream>>>(part, n, y, dis, u, u2, b, out);
    }
}

// Round 7
// 57.652 us; speedup vs baseline: 4.9494x; 4.9494x over previous
//
#include <hip/hip_runtime.h>

// SGC: out = A^K (x w) + b, A = D^-1/2 (Adj+I) D^-1/2, K=2, on per-node scalars y = x.w.
// Evidence log:
//  R1/R2: per-edge device atomics ~0.53 TB/s effective (32B/atomic) -> 48us/pass. Dead.
//  R2 accounting: graph-replay dispatch gap ~0.2us/kernel -> multi-kernel is fine.
//  R6: cooperative grid.sync + 49-block phases = 285us. Dead.
//  R7 (this): zero device atomics in fast path. Fixed per-(tile8192,chunk) bucket layout
//  (mean run 167, cap 256 = +7sigma), LDS counting-sort k_bin fused with k_dot in one
//  dispatch (disjoint block ranges). 7 dispatches total.

#define CHUNK_LG  10
#define CHUNK     1024
#define NCHMAX    64
#define TILEA     8192
#define CAPR      256       // slots per (tile,chunk) run
#define NS        8         // hop slabs per chunk

// ---------- A: blocks [0,nbin) bin one 8192-edge tile; blocks [nbin,..) compute y = x.w ----------
__global__ __launch_bounds__(256)
void ka_bin_dot(const float* __restrict__ x, const int* __restrict__ src,
                const int* __restrict__ dst, const float* __restrict__ W,
                int n, int E, int nbin,
                unsigned* __restrict__ binned, int* __restrict__ bcnt,
                float* __restrict__ y)
{
    __shared__ unsigned raw[TILEA];                    // 32 KB
    __shared__ int hist[NCHMAX], base_[NCHMAX], cur[NCHMAX];
    const int t   = threadIdx.x;
    const int bid = blockIdx.x;

    if (bid < nbin) {
        if (t < NCHMAX) hist[t] = 0;
        __syncthreads();
        const int e0 = bid * TILEA;
        int nrec = E - e0; if (nrec > TILEA) nrec = TILEA;
        #pragma unroll
        for (int k = 0; k < TILEA / 256; k++) {
            int j = k * 256 + t;
            if (j < nrec) {
                int e = e0 + j;
                int s = src[e], d = dst[e];
                int ch = d >> CHUNK_LG;
                raw[j] = ((unsigned)ch << 26) | ((unsigned)(d & (CHUNK - 1)) << 16) | (unsigned)s;
                atomicAdd(&hist[ch], 1);
            }
        }
        __syncthreads();
        if (t < 64) {                                   // wave-0 scan over 64 buckets
            int h = hist[t], v = h;
            #pragma unroll
            for (int off = 1; off < 64; off <<= 1) {
                int w = __shfl_up(v, off);
                if (t >= off) v += w;
            }
            base_[t] = v - h; cur[t] = v - h;
            bcnt[bid * NCHMAX + t] = (h > CAPR) ? CAPR : h;
        }
        __syncthreads();
        #pragma unroll
        for (int k = 0; k < TILEA / 256; k++) {
            int j = k * 256 + t;
            if (j < nrec) {
                unsigned r = raw[j];
                int ch  = r >> 26;
                int pos = atomicAdd(&cur[ch], 1) - base_[ch];
                if (pos < CAPR)
                    binned[(((size_t)(bid * NCHMAX + ch)) << 8) + pos] = r & 0x03FFFFFFu;
            }
        }
    } else {
        int i = (bid - nbin) * 4 + (t >> 6);            // one wave per node
        if (i < n) {
            int lane = t & 63;
            float2 wv = ((const float2*)W)[lane];
            float2 xv = ((const float2*)(x + (size_t)i * 128))[lane];
            float v = xv.x * wv.x + xv.y * wv.y;
            #pragma unroll
            for (int off = 32; off; off >>= 1) v += __shfl_xor(v, off);
            if (lane == 0) y[i] = v;
        }
    }
}

// ---------- hop: block (c,m) accumulates slab m of chunk c in LDS; coalesced partial write ----------
template <int MODE>   // 0: degree (val=1), 1: sum val[src]
__global__ __launch_bounds__(256)
void kb_hop(const unsigned* __restrict__ binned, const int* __restrict__ bcnt,
            int ntiles, const float* __restrict__ val, float* __restrict__ partial)
{
    __shared__ float acc[CHUNK];
    const int c = blockIdx.x >> 3;                      // / NS
    const int m = blockIdx.x & (NS - 1);
    const int t = threadIdx.x;
    #pragma unroll
    for (int k = 0; k < CHUNK / 256; k++) acc[t + k * 256] = 0.f;
    __syncthreads();
    for (int b = m; b < ntiles; b += NS) {
        int len = bcnt[b * NCHMAX + c];
        const unsigned* run = binned + (((size_t)(b * NCHMAX + c)) << 8);
        for (int j = t; j < len; j += 256) {
            unsigned r = run[j];
            float v = (MODE == 0) ? 1.0f : val[r & 0xFFFFu];
            atomicAdd(&acc[r >> 16], v);                // ds_add_f32; r>>16 = dst_local
        }
    }
    __syncthreads();
    float* pp = partial + (((size_t)(c * NS + m)) << CHUNK_LG);
    #pragma unroll
    for (int k = 0; k < CHUNK / 256; k++) pp[t + k * 256] = acc[t + k * 256];
}

// ---------- reduce slabs + epilogue ----------
// V0: dis=rsqrt(deg+1), u=dis*y   V1: u2=dis^2*(s+u)   V2: out=dis*(s+u2)+b
template <int V>
__global__ __launch_bounds__(256)
void kc_red(const float* __restrict__ partial, int n,
            const float* __restrict__ y, float* __restrict__ dis,
            float* __restrict__ u, float* __restrict__ u2,
            const float* __restrict__ bias, float* __restrict__ out)
{
    int c = blockIdx.x;
    #pragma unroll
    for (int k = 0; k < CHUNK / 256; k++) {
        int l = k * 256 + threadIdx.x;
        int i = (c << CHUNK_LG) + l;
        if (i >= n) continue;
        const float* pp = partial + (((size_t)(c * NS)) << CHUNK_LG) + l;
        float s = 0.f;
        #pragma unroll
        for (int m = 0; m < NS; m++) s += pp[m << CHUNK_LG];
        if (V == 0) { float d = rsqrtf(s + 1.0f); dis[i] = d; u[i] = d * y[i]; }
        if (V == 1) { float d = dis[i]; u2[i] = d * d * (s + u[i]); }
        if (V == 2) { out[i] = dis[i] * (s + u2[i]) + bias[0]; }
    }
}

// ---------------- fallback (R5 proven path, ~63 us) ----------------
#define NSLAB 16
#define RECS  7

__global__ void k_zero(int* __restrict__ cnt) { cnt[threadIdx.x] = 0; }

__global__ void k_bin(const int* __restrict__ src, const int* __restrict__ dst,
                      int E, int nchunks, int cap,
                      int* __restrict__ cnt, unsigned int* __restrict__ binned) {
    __shared__ int hist[NCHMAX], base[NCHMAX], cur[NCHMAX];
    int t = threadIdx.x;
    if (t < NCHMAX) { hist[t] = 0; cur[t] = 0; }
    __syncthreads();
    int e0 = blockIdx.x * (RECS * 256);
    unsigned int rec[RECS]; int ch[RECS];
    #pragma unroll
    for (int k = 0; k < RECS; k++) {
        int e = e0 + k * 256 + t;
        if (e < E) {
            int s = src[e], d = dst[e];
            ch[k]  = d >> CHUNK_LG;
            rec[k] = ((unsigned)(d & (CHUNK - 1)) << 16) | (unsigned)s;
            atomicAdd(&hist[ch[k]], 1);
        } else ch[k] = -1;
    }
    __syncthreads();
    if (t < nchunks) base[t] = atomicAdd(&cnt[t], hist[t]);
    __syncthreads();
    #pragma unroll
    for (int k = 0; k < RECS; k++) {
        if (ch[k] >= 0) {
            int slot = base[ch[k]] + atomicAdd(&cur[ch[k]], 1);
            if (slot < cap) binned[(size_t)ch[k] * cap + slot] = rec[k];
        }
    }
}

template <int MODE>
__global__ void k_hop(const unsigned int* __restrict__ binned, const int* __restrict__ cnt,
                      int cap, const float* __restrict__ val, float* __restrict__ partial) {
    __shared__ float acc[CHUNK];
    int c = blockIdx.x >> 4;
    int m = blockIdx.x & (NSLAB - 1);
    int t = threadIdx.x;
    #pragma unroll
    for (int k = 0; k < CHUNK / 256; k++) acc[t + k * 256] = 0.f;
    __syncthreads();
    int nc = cnt[c]; if (nc > cap) nc = cap;
    const unsigned int* bb = binned + (size_t)c * cap;
    for (int e = m * 256 + t; e < nc; e += NSLAB * 256) {
        unsigned int r = bb[e];
        float v = (MODE == 0) ? 1.0f : val[r & 0xFFFFu];
        atomicAdd(&acc[r >> 16], v);
    }
    __syncthreads();
    float* pp = partial + ((size_t)(c * NSLAB + m) << CHUNK_LG);
    #pragma unroll
    for (int k = 0; k < CHUNK / 256; k++) pp[t + k * 256] = acc[t + k * 256];
}

__global__ void k_dot(const float* __restrict__ x, const float* __restrict__ W,
                      float* __restrict__ y, int n) {
    int wid  = (blockIdx.x * blockDim.x + threadIdx.x) >> 6;
    int lane = threadIdx.x & 63;
    if (wid >= n) return;
    float2 xv = ((const float2*)(x + (size_t)wid * 128))[lane];
    float2 wv = ((const float2*)W)[lane];
    float v = xv.x * wv.x + xv.y * wv.y;
    #pragma unroll
    for (int off = 32; off; off >>= 1) v += __shfl_xor(v, off);
    if (lane == 0) y[wid] = v;
}

template <int V>
__global__ void k_reduce(const float* __restrict__ partial, int n,
                         const float* __restrict__ y, float* __restrict__ dis,
                         float* __restrict__ u, float* __restrict__ u2,
                         const float* __restrict__ b, float* __restrict__ out) {
    int i = blockIdx.x * blockDim.x + threadIdx.x;
    if (i >= n) return;
    int c = i >> CHUNK_LG, l = i & (CHUNK - 1);
    const float* pp = partial + ((size_t)(c * NSLAB) << CHUNK_LG) + l;
    float s = 0.f;
    #pragma unroll
    for (int m = 0; m < NSLAB; m++) s += pp[m << CHUNK_LG];
    if (V == 0) { float d = rsqrtf(s + 1.0f); dis[i] = d; u[i] = d * y[i]; }
    if (V == 1) { float d = dis[i]; u2[i] = d * d * (s + u[i]); }
    if (V == 2) { out[i] = dis[i] * (s + u2[i]) + b[0]; }
}

extern "C" void kernel_launch(void* const* d_in, const int* in_sizes, int n_in,
                              void* d_out, int out_size, void* d_ws, size_t ws_size,
                              hipStream_t stream) {
    const float* x  = (const float*)d_in[0];
    const int*   ei = (const int*)d_in[1];   // [2,E]; row0=src, row1=dst
    const float* W  = (const float*)d_in[2];
    const float* b  = (const float*)d_in[3];
    float* out = (float*)d_out;

    const int n = out_size;            // 50000
    const int E = in_sizes[1] / 2;     // 800000
    const int D = in_sizes[0] / n;     // 128
    const int* src = ei;
    const int* dst = ei + E;

    const int C      = (n + CHUNK - 1) >> CHUNK_LG;        // 49
    const int ntiles = (E + TILEA - 1) / TILEA;            // 98

    // fast-path ws (words): binned | bcnt | partial | y | dis | u | u2
    size_t w_binned = (size_t)ntiles * NCHMAX * CAPR;
    size_t w_bcnt   = (size_t)ntiles * NCHMAX;
    size_t w_part   = (size_t)C * NS * CHUNK;
    size_t need     = (w_binned + w_bcnt + w_part + 4 * (size_t)n) * 4;

    if (D == 128 && n <= 65536 && C <= NCHMAX && ws_size >= need) {
        unsigned* binned = (unsigned*)d_ws;
        int*      bcnt   = (int*)d_ws + w_binned;
        float*    part   = (float*)d_ws + w_binned + w_bcnt;
        float*    y      = part + w_part;
        float*    dis    = y + n;
        float*    u      = dis + n;
        float*    u2     = u + n;

        const int dotBlocks = (n + 3) / 4;                 // one wave per node
        const int gridA     = ntiles + dotBlocks;
        const int hopBlocks = C * NS;

        ka_bin_dot<<<gridA, 256, 0, stream>>>(x, src, dst, W, n, E, ntiles, binned, bcnt, y);
        kb_hop<0><<<hopBlocks, 256, 0, stream>>>(binned, bcnt, ntiles, y, part);      // degree
        kc_red<0><<<C, 256, 0, stream>>>(part, n, y, dis, u, u2, b, out);
        kb_hop<1><<<hopBlocks, 256, 0, stream>>>(binned, bcnt, ntiles, u, part);      // hop 1
        kc_red<1><<<C, 256, 0, stream>>>(part, n, y, dis, u, u2, b, out);
        kb_hop<1><<<hopBlocks, 256, 0, stream>>>(binned, bcnt, ntiles, u2, part);     // hop 2
        kc_red<2><<<C, 256, 0, stream>>>(part, n, y, dis, u, u2, b, out);
        return;
    }

    // fallback: R5 proven binned multi-kernel path
    {
        const int TBf = 256;
        const int cap = (int)((long long)E * 5 / (4 * C)) + 512;
        int*          cnt    = (int*)d_ws;
        unsigned int* binned = (unsigned int*)(cnt + 64);
        float*        part   = (float*)(binned + (size_t)C * cap);
        float*        y      = part + (size_t)C * NSLAB * CHUNK;
        float*        dis    = y + n;
        float*        u      = dis + n;
        float*        u2     = u + n;

        const int binBlocks = (E + RECS * 256 - 1) / (RECS * 256);
        const int hopBlocks = C * NSLAB;
        const int nb        = (n + TBf - 1) / TBf;
        const int dotBlocks = ((size_t)n * 64 + TBf - 1) / TBf;

        k_zero<<<1, 64, 0, stream>>>(cnt);
        k_bin<<<binBlocks, TBf, 0, stream>>>(src, dst, E, C, cap, cnt, binned);
        k_dot<<<dotBlocks, TBf, 0, stream>>>(x, W, y, n);
        k_hop<0><<<hopBlocks, TBf, 0, stream>>>(binned, cnt, cap, y, part);
        k_reduce<0><<<nb, TBf, 0, stream>>>(part, n, y, dis, u, u2, b, out);
        k_hop<1><<<hopBlocks, TBf, 0, stream>>>(binned, cnt, cap, u, part);
        k_reduce<1><<<nb, TBf, 0, stream>>>(part, n, y, dis, u, u2, b, out);
        k_hop<1><<<hopBlocks, TBf, 0, stream>>>(binned, cnt, cap, u2, part);
        k_reduce<2><<<nb, TBf, 0, stream>>>(part, n, y, dis, u, u2, b, out);
    }
}